// Round 2
// baseline (132.396 us; speedup 1.0000x reference)
//
#include <hip/hip_runtime.h>

typedef short bf16x8 __attribute__((ext_vector_type(8)));
typedef short bf16x4 __attribute__((ext_vector_type(4)));
typedef float f32x4 __attribute__((ext_vector_type(4)));
typedef float f32x16 __attribute__((ext_vector_type(16)));
typedef unsigned short u16;
typedef unsigned int u32;
typedef u16 u16x8 __attribute__((ext_vector_type(8)));
typedef u16 u16x4 __attribute__((ext_vector_type(4)));

#define DEV __device__ __forceinline__

DEV u16 f2bf(float f) {
  unsigned u = __float_as_uint(f);
  u += 0x7fff + ((u >> 16) & 1);  // RNE (no NaN in this workload)
  return (u16)(u >> 16);
}

// pack 2 fp32 -> 2 bf16 in one v_perm_b32 (round-half-up; fine for P values)
DEV int pkbf(float lo, float hi) {
  return __builtin_amdgcn_perm(__float_as_uint(hi) + 0x8000u,
                               __float_as_uint(lo) + 0x8000u, 0x07060302u);
}

#define MFMA16(a, b, c) __builtin_amdgcn_mfma_f32_16x16x32_bf16(a, b, c, 0, 0, 0)
#define MFMA3216(a, b, c) __builtin_amdgcn_mfma_f32_32x32x16_bf16(a, b, c, 0, 0, 0)

#if __has_builtin(__builtin_amdgcn_mfma_f32_32x32x8bf16_1k)
#define HAVE_PV8 1
#define PVMFMA(a, b, c) __builtin_amdgcn_mfma_f32_32x32x8bf16_1k(a, b, c, 0, 0, 0)
#else
#define HAVE_PV8 0
#endif

// exp base: fold log2(e) into the Q scale when raw v_exp_f32 is reachable
#if __has_builtin(__builtin_amdgcn_exp2f)
#define QSCALE 0.18033688011112042f  // 0.125 * log2(e)
#define EXPFN(x) __builtin_amdgcn_exp2f(x)
#else
#define QSCALE 0.125f
#define EXPFN(x) __expf(x)
#endif

// global -> LDS direct DMA, 16B per lane; LDS dest = uniform base + lane*16
#define GLD16(gp, lp)                                                     \
  __builtin_amdgcn_global_load_lds(                                       \
      (const __attribute__((address_space(1))) u32*)(gp),                 \
      (__attribute__((address_space(3))) u32*)(lp), 16, 0, 0)

// ---------------------------------------------------------------------------
// wprep: transpose+convert weights to bf16 [n][k]; ALSO pre-convert x1/x2 to
// bf16 (blocks >= 1024) so qkv_gemm never touches fp32 in its K-loop.
// ---------------------------------------------------------------------------
__global__ __launch_bounds__(256) void wprep(
    const float* __restrict__ Wqk, const float* __restrict__ Wv,
    const float* __restrict__ Wout,
    const float* __restrict__ x1, const float* __restrict__ x2,
    u16* __restrict__ WqkT, u16* __restrict__ WvT, u16* __restrict__ WoutT,
    u16* __restrict__ x1b, u16* __restrict__ x2b) {
  __shared__ float tf[32][33];
  int bx = blockIdx.x, t = threadIdx.x;
  if (bx >= 1024) {
    int id = bx - 1024;  // 0..2047
    const float* src = id < 1024 ? x1 : x2;
    u16* dst = id < 1024 ? x1b : x2b;
    long base = (long)(id & 1023) * 2048 + t * 8;
    float4 f0 = *(const float4*)(src + base);
    float4 f1 = *(const float4*)(src + base + 4);
    u16x8 o;
    o[0] = f2bf(f0.x); o[1] = f2bf(f0.y); o[2] = f2bf(f0.z); o[3] = f2bf(f0.w);
    o[4] = f2bf(f1.x); o[5] = f2bf(f1.y); o[6] = f2bf(f1.z); o[7] = f2bf(f1.w);
    *(u16x8*)(dst + base) = o;
    return;
  }
  const float* src; u16* dst; int Ncols; int id;
  if (bx < 512)      { id = bx;       src = Wqk;  dst = WqkT;  Ncols = 1024; }
  else if (bx < 768) { id = bx - 512; src = Wv;   dst = WvT;   Ncols = 512; }
  else               { id = bx - 768; src = Wout; dst = WoutT; Ncols = 512; }
  int tilesPerRow = Ncols >> 5;
  int tr = id / tilesPerRow, tc = id % tilesPerRow;
  int r0 = tr * 32, c0 = tc * 32;
  {
    int r = t >> 3, c4 = (t & 7) * 4;
    float4 v = *(const float4*)(src + (long)(r0 + r) * Ncols + c0 + c4);
    tf[r][c4] = v.x; tf[r][c4 + 1] = v.y; tf[r][c4 + 2] = v.z; tf[r][c4 + 3] = v.w;
  }
  __syncthreads();
  {
    int c = t >> 3, r4 = (t & 7) * 4;
    u16x4 o;
    o[0] = f2bf(tf[r4][c]); o[1] = f2bf(tf[r4 + 1][c]);
    o[2] = f2bf(tf[r4 + 2][c]); o[3] = f2bf(tf[r4 + 3][c]);
    *(u16x4*)(dst + (long)(c0 + c) * 512 + r0 + r4) = o;
  }
}

// ---------------------------------------------------------------------------
// Fused QKV GEMM v3 (m97-style): 128x128 tile, BK=32, 4 waves of 64x64,
// global_load_lds staging into linear LDS with T2 both-sides XOR swizzle:
//   store position p of row r holds global k-chunk p ^ ((r>>1)&3)
//   (achieved by inverse-swizzling the per-lane GLOBAL source address),
//   frag read of chunk q reads position q ^ ((r>>1)&3)  -> conflict-free.
// Zero staging VGPRs/VALU/ds_writes. Grid 384 = 128 (Q) + 256 (KV).
// ---------------------------------------------------------------------------
__global__ __launch_bounds__(256) void qkv_gemm(
    const u16* __restrict__ x1b, const u16* __restrict__ x2b,
    const u16* __restrict__ WqkT, const u16* __restrict__ WvT,
    u16* __restrict__ out_q, u16* __restrict__ out_k, u16* __restrict__ out_vt) {
  __shared__ u16 sA[2][128 * 32];
  __shared__ u16 sB[2][128 * 32];
  int bx = blockIdx.x, t = threadIdx.x;
  bool isQ = bx < 128;
  int bx2 = isQ ? bx : bx - 128;
  const u16* Ap = isQ ? x2b : x1b;
  const u16* BT = isQ ? WvT : WqkT;
  int m0 = (bx2 & 31) * 128, n0 = (bx2 >> 5) * 128;
  int w = t >> 6, l = t & 63, lm = l & 15, lq = l >> 4;
  int wr = w >> 1, wc = w & 1;

  f32x4 zero = {0.f, 0.f, 0.f, 0.f};
  f32x4 acc[4][4];
#pragma unroll
  for (int i = 0; i < 4; ++i)
#pragma unroll
    for (int j = 0; j < 4; ++j) acc[i][j] = zero;

  // per-lane DMA source: row = base + l>>2, stored chunk (l&3) holds global
  // chunk (l&3) ^ ((row>>1)&3) = (l&3) ^ ((l>>3)&3)   (base rows are mult of 16)
  int srow = w * 16 + (l >> 2);
  int swzk = ((l & 3) ^ ((l >> 3) & 3)) * 8;
  const u16* gAsrc = Ap + (long)(m0 + srow) * 512 + swzk;
  const u16* gBsrc = BT + (long)(n0 + srow) * 512 + swzk;

  auto stage = [&](int kt, int buf) {
    const u16* a0 = gAsrc + kt * 32;
    const u16* b0 = gBsrc + kt * 32;
    GLD16(a0,            sA[buf] + w * 512);
    GLD16(a0 + 64 * 512, sA[buf] + 2048 + w * 512);
    GLD16(b0,            sB[buf] + w * 512);
    GLD16(b0 + 64 * 512, sB[buf] + 2048 + w * 512);
  };

  stage(0, 0);
  __syncthreads();

  // frag read offsets: row_local*32 + (lq ^ ((lm>>1)&3))*8
  int rchunk = (lq ^ ((lm >> 1) & 3)) * 8;
  int frA = (wr * 64 + lm) * 32 + rchunk;
  int frB = (wc * 64 + lm) * 32 + rchunk;

  for (int kt = 0; kt < 16; ++kt) {
    int cur = kt & 1;
    if (kt < 15) stage(kt + 1, cur ^ 1);
    bf16x8 af[4], bfr[4];
#pragma unroll
    for (int ms = 0; ms < 4; ++ms)
      af[ms] = *(const bf16x8*)(sA[cur] + frA + ms * 512);
#pragma unroll
    for (int s = 0; s < 4; ++s)
      bfr[s] = *(const bf16x8*)(sB[cur] + frB + s * 512);
#pragma unroll
    for (int ms = 0; ms < 4; ++ms)
#pragma unroll
      for (int s = 0; s < 4; ++s)
        acc[ms][s] = MFMA16(af[ms], bfr[s], acc[ms][s]);
    __syncthreads();  // waves drain own DMA before barrier -> next buf ready
  }

#pragma unroll
  for (int ms = 0; ms < 4; ++ms) {
    int gmBase = m0 + wr * 64 + ms * 16 + lq * 4;
    int b = gmBase >> 11, n = gmBase & 2047;
#pragma unroll
    for (int s = 0; s < 4; ++s) {
      int gc = n0 + wc * 64 + s * 16 + lm;
      if (isQ) {
#pragma unroll
        for (int r = 0; r < 4; ++r)
          out_q[(((long)(b << 3) + (gc >> 6)) * 2048 + n + r) * 64 + (gc & 63)] =
              f2bf(acc[ms][s][r] * QSCALE);
      } else if (gc < 512) {
#pragma unroll
        for (int r = 0; r < 4; ++r)
          out_k[(((long)(b << 3) + (gc >> 6)) * 2048 + n + r) * 64 + (gc & 63)] =
              f2bf(acc[ms][s][r]);
      } else {
        int c = gc - 512, h = c >> 6, d = c & 63;
        u16x4 vv;
#pragma unroll
        for (int r = 0; r < 4; ++r) vv[r] = f2bf(acc[ms][s][r]);
        *(u16x4*)(out_vt + (((long)(b << 3) + h) * 64 + d) * 2048 + n) = vv;
      }
    }
  }
}

// ---------------------------------------------------------------------------
// Attention v5: double-buffered DMA staging (unchanged) + tree-summed dacc
// (breaks the 32-long serial dependent-add chain) + s_setprio around MFMA
// clusters (T5).
// ---------------------------------------------------------------------------
__global__ __launch_bounds__(256, 2) void attn(
    const u16* __restrict__ Q, const u16* __restrict__ K,
    const u16* __restrict__ Vt, u16* __restrict__ O) {
  int id = blockIdx.x;
  int bh = id & 15, qt = id >> 4;
  int b = bh >> 3, h = bh & 7;
  const u16* Kh = K + (long)bh * 2048 * 64;
  const u16* Vh = Vt + (long)bh * 64 * 2048;
  int t = threadIdx.x, w = t >> 6, lane = t & 63, ln = lane & 31, hi = lane >> 5;
  int g = w & 1, kh = w >> 1;

  __shared__ u16 smem[2][2][2][4096];  // [buf][K/V][kh][64 rows x 64 elems, swizzled]

  bf16x8 qf[4];
  {
    const u16* qp = Q + (long)bh * 2048 * 64 + (long)(qt * 64 + g * 32 + ln) * 64 + hi * 8;
#pragma unroll
    for (int dc = 0; dc < 4; ++dc) qf[dc] = *(const bf16x8*)(qp + dc * 16);
  }

  f32x16 accO[2];
#pragma unroll
  for (int dt = 0; dt < 2; ++dt)
#pragma unroll
    for (int i = 0; i < 16; ++i) accO[dt][i] = 0.f;
  float dacc = 0.f;

  int lrow = lane >> 3;                 // 0..7
  int swz = ((lane & 7) ^ lrow) * 8;    // element offset of 16B chunk in row
  const u16* gKl = Kh + (long)(kh * 1024 + g * 32 + lrow) * 64 + swz;
  const u16* gVl = Vh + (long)(g * 32 + lrow) * 2048 + kh * 1024 + swz;

  auto stage = [&](int jt, int buf) {
    u16* sK = smem[buf][0][kh];
    u16* sV = smem[buf][1][kh];
    const u16* gk = gKl + (long)jt * 4096;
    const u16* gv = gVl + jt * 64;
#pragma unroll
    for (int i = 0; i < 4; ++i) {
      GLD16(gk + i * 512, sK + (g * 32 + i * 8) * 64);
      GLD16(gv + (long)i * 16384, sV + (g * 32 + i * 8) * 64);
    }
  };

  stage(0, 0);
  __syncthreads();

  int swl = ln & 7;
  for (int jt = 0; jt < 16; ++jt) {
    int cur = jt & 1;
    if (jt < 15) stage(jt + 1, cur ^ 1);  // issue next-tile DMA before compute
    const u16* sKh = smem[cur][0][kh];
    const u16* sVh = smem[cur][1][kh];
#pragma unroll
    for (int kt2 = 0; kt2 < 2; ++kt2) {
      int rowK = (kt2 * 32 + ln) * 64;
      f32x16 st1, st2;
#pragma unroll
      for (int i = 0; i < 16; ++i) { st1[i] = 0.f; st2[i] = 0.f; }
      bf16x8 kf0 = *(const bf16x8*)(sKh + rowK + ((0 * 2 + hi) ^ swl) * 8);
      bf16x8 kf1 = *(const bf16x8*)(sKh + rowK + ((1 * 2 + hi) ^ swl) * 8);
      bf16x8 kf2 = *(const bf16x8*)(sKh + rowK + ((2 * 2 + hi) ^ swl) * 8);
      bf16x8 kf3 = *(const bf16x8*)(sKh + rowK + ((3 * 2 + hi) ^ swl) * 8);
      __builtin_amdgcn_s_setprio(1);
      st1 = MFMA3216(kf0, qf[0], st1);
      st2 = MFMA3216(kf1, qf[1], st2);
      st1 = MFMA3216(kf2, qf[2], st1);
      st2 = MFMA3216(kf3, qf[3], st2);
      __builtin_amdgcn_s_setprio(0);
      float p[16];
#pragma unroll
      for (int i = 0; i < 16; ++i) p[i] = EXPFN(st1[i] + st2[i]);
      // pairwise tree: 15 mostly-independent adds instead of a 16-deep chain
      float q0 = (p[0] + p[1]) + (p[2] + p[3]);
      float q1 = (p[4] + p[5]) + (p[6] + p[7]);
      float q2 = (p[8] + p[9]) + (p[10] + p[11]);
      float q3 = (p[12] + p[13]) + (p[14] + p[15]);
      dacc += (q0 + q1) + (q2 + q3);
#if HAVE_PV8
      __builtin_amdgcn_s_setprio(1);
#pragma unroll
      for (int c = 0; c < 4; ++c) {
        union { int2 i2; bf16x4 v; } u;
        u.i2.x = pkbf(p[c * 4 + 0], p[c * 4 + 1]);
        u.i2.y = pkbf(p[c * 4 + 2], p[c * 4 + 3]);
#pragma unroll
        for (int dt = 0; dt < 2; ++dt) {
          bf16x4 vf = *(const bf16x4*)(sVh + (dt * 32 + ln) * 64 +
                                       (((kt2 * 4 + c) ^ swl) * 8) + hi * 4);
          accO[dt] = PVMFMA(vf, u.v, accO[dt]);
        }
      }
      __builtin_amdgcn_s_setprio(0);
#else
      __builtin_amdgcn_s_setprio(1);
#pragma unroll
      for (int c2 = 0; c2 < 2; ++c2) {
        int o0x = pkbf(p[c2 * 8 + 0], p[c2 * 8 + 1]);
        int o0y = pkbf(p[c2 * 8 + 2], p[c2 * 8 + 3]);
        int o1x = pkbf(p[c2 * 8 + 4], p[c2 * 8 + 5]);
        int o1y = pkbf(p[c2 * 8 + 6], p[c2 * 8 + 7]);
        int s0x = __shfl_xor(o0x, 32), s0y = __shfl_xor(o0y, 32);
        int s1x = __shfl_xor(o1x, 32), s1y = __shfl_xor(o1y, 32);
        union { int4 i4; bf16x8 v; } u;
        if (hi) { u.i4.x = s1x; u.i4.y = s1y; u.i4.z = o1x; u.i4.w = o1y; }
        else    { u.i4.x = o0x; u.i4.y = o0y; u.i4.z = s0x; u.i4.w = s0y; }
#pragma unroll
        for (int dt = 0; dt < 2; ++dt) {
          bf16x8 vf = *(const bf16x8*)(sVh + (dt * 32 + ln) * 64 +
                                       (((kt2 * 4 + c2 * 2 + hi) ^ swl) * 8));
          accO[dt] = MFMA3216(vf, u.v, accO[dt]);
        }
      }
      __builtin_amdgcn_s_setprio(0);
#endif
    }
    __syncthreads();  // syncs consumers of buf[cur] AND drains this wave's DMA
  }

  // combine key-halves via LDS scratch (aliases smem; loop ended on a barrier)
  float* cb = (float*)&smem[0][0][0][0];
  float* base = cb + g * 2112;
  if (kh == 1) {
#pragma unroll
    for (int dt = 0; dt < 2; ++dt)
#pragma unroll
      for (int i = 0; i < 16; ++i)
        base[(dt * 16 + i) * 64 + hi * 32 + ln] = accO[dt][i];
    base[2048 + hi * 32 + ln] = dacc;
  }
  __syncthreads();
  if (kh == 0) {
#pragma unroll
    for (int dt = 0; dt < 2; ++dt)
#pragma unroll
      for (int i = 0; i < 16; ++i)
        accO[dt][i] += base[(dt * 16 + i) * 64 + hi * 32 + ln];
    dacc += base[2048 + hi * 32 + ln];
    dacc += __shfl_xor(dacc, 32);
    float inv = 1.f / dacc;

    u16* Ob = O + ((long)b * 2048 + qt * 64 + g * 32 + ln) * 512 + h * 64;
#pragma unroll
    for (int dt = 0; dt < 2; ++dt)
#pragma unroll
      for (int gq = 0; gq < 4; ++gq) {
        u16x4 o;
#pragma unroll
        for (int rr = 0; rr < 4; ++rr) o[rr] = f2bf(accO[dt][gq * 4 + rr] * inv);
        *(u16x4*)(Ob + dt * 32 + gq * 8 + hi * 4) = o;
      }
  }
}

// ---------------------------------------------------------------------------
// out GEMM v2: same m97-style template, 128x128 tile, grid 128 blocks.
// A (O) re-read drops 16x -> 4x; per-wave 16 MFMA / 8 ds_read per K-step.
// ---------------------------------------------------------------------------
__global__ __launch_bounds__(256) void out_gemm(
    const u16* __restrict__ A, const u16* __restrict__ BT,
    float* __restrict__ out_f, const float* __restrict__ bias) {
  __shared__ u16 sA[2][128 * 32];
  __shared__ u16 sB[2][128 * 32];
  int bx = blockIdx.x, t = threadIdx.x;
  int m0 = (bx & 31) * 128, n0 = (bx >> 5) * 128;
  int w = t >> 6, l = t & 63, lm = l & 15, lq = l >> 4;
  int wr = w >> 1, wc = w & 1;

  f32x4 zero = {0.f, 0.f, 0.f, 0.f};
  f32x4 acc[4][4];
#pragma unroll
  for (int i = 0; i < 4; ++i)
#pragma unroll
    for (int j = 0; j < 4; ++j) acc[i][j] = zero;

  int srow = w * 16 + (l >> 2);
  int swzk = ((l & 3) ^ ((l >> 3) & 3)) * 8;
  const u16* gAsrc = A + (long)(m0 + srow) * 512 + swzk;
  const u16* gBsrc = BT + (long)(n0 + srow) * 512 + swzk;

  auto stage = [&](int kt, int buf) {
    const u16* a0 = gAsrc + kt * 32;
    const u16* b0 = gBsrc + kt * 32;
    GLD16(a0,            sA[buf] + w * 512);
    GLD16(a0 + 64 * 512, sA[buf] + 2048 + w * 512);
    GLD16(b0,            sB[buf] + w * 512);
    GLD16(b0 + 64 * 512, sB[buf] + 2048 + w * 512);
  };

  stage(0, 0);
  __syncthreads();

  int rchunk = (lq ^ ((lm >> 1) & 3)) * 8;
  int frA = (wr * 64 + lm) * 32 + rchunk;
  int frB = (wc * 64 + lm) * 32 + rchunk;

  for (int kt = 0; kt < 16; ++kt) {
    int cur = kt & 1;
    if (kt < 15) stage(kt + 1, cur ^ 1);
    bf16x8 af[4], bfr[4];
#pragma unroll
    for (int ms = 0; ms < 4; ++ms)
      af[ms] = *(const bf16x8*)(sA[cur] + frA + ms * 512);
#pragma unroll
    for (int s = 0; s < 4; ++s)
      bfr[s] = *(const bf16x8*)(sB[cur] + frB + s * 512);
#pragma unroll
    for (int ms = 0; ms < 4; ++ms)
#pragma unroll
      for (int s = 0; s < 4; ++s)
        acc[ms][s] = MFMA16(af[ms], bfr[s], acc[ms][s]);
    __syncthreads();
  }

#pragma unroll
  for (int ms = 0; ms < 4; ++ms) {
    int gm = m0 + wr * 64 + ms * 16 + lq * 4;
#pragma unroll
    for (int s = 0; s < 4; ++s) {
      int gc = n0 + wc * 64 + s * 16 + lm;
      float bv = bias[gc];
#pragma unroll
      for (int r = 0; r < 4; ++r)
        out_f[(long)(gm + r) * 512 + gc] = acc[ms][s][r] + bv;
    }
  }
}

// ---------------------------------------------------------------------------
extern "C" void kernel_launch(void* const* d_in, const int* in_sizes, int n_in,
                              void* d_out, int out_size, void* d_ws, size_t ws_size,
                              hipStream_t stream) {
  const float* x1 = (const float*)d_in[0];
  const float* x2 = (const float*)d_in[1];
  const float* Wqk = (const float*)d_in[2];
  const float* Wv = (const float*)d_in[3];
  const float* Wout = (const float*)d_in[4];
  const float* bout = (const float*)d_in[5];
  float* out = (float*)d_out;

  u16* ws = (u16*)d_ws;
  const long SZ = 2097152;  // 2*8*2048*64
  u16* Qw = ws;
  u16* Kw = ws + SZ;
  u16* Vtw = ws + 2 * SZ;
  u16* Ow = ws + 3 * SZ;
  u16* WqkT = ws + 4 * SZ;
  u16* WvT = WqkT + 524288;
  u16* WoutT = WvT + 262144;
  u16* x1b = WoutT + 262144;
  u16* x2b = x1b + SZ;

  wprep<<<3072, 256, 0, stream>>>(Wqk, Wv, Wout, x1, x2, WqkT, WvT, WoutT, x1b, x2b);
  qkv_gemm<<<384, 256, 0, stream>>>(x1b, x2b, WqkT, WvT, Qw, Kw, Vtw);
  attn<<<512, 256, 0, stream>>>(Qw, Kw, Vtw, Ow);
  out_gemm<<<128, 256, 0, stream>>>(Ow, WoutT, out, bout);
}